// Round 9
// baseline (2681.964 us; speedup 1.0000x reference)
//
#include <hip/hip_runtime.h>
#include <hip/hip_fp16.h>
#include <stdint.h>

#define Bsz 64
#define Tsz 1024
#define Dsz 256
#define UNITSn 256
#define Zdim 1024      // 4*UNITS

typedef _Float16 f16x8  __attribute__((ext_vector_type(8)));
typedef float    f32x4  __attribute__((ext_vector_type(4)));

// Single-instruction 2-MAC f16 dot with f32 accumulate (VGPR operands only).
#define DOT2V(acc, w, h) asm("v_dot2_f32_f16 %0, %1, %2, %0" : "+v"(acc) : "v"(w), "v"(h))
#define DOT4V(acc, w4, h4) { DOT2V(acc, (w4).x, (h4).x); DOT2V(acc, (w4).y, (h4).y); \
                             DOT2V(acc, (w4).z, (h4).z); DOT2V(acc, (w4).w, (h4).w); }
// AGPR storage: write at init, read (VALU, no memory latency) per use.
#define WR_A(dst, src) asm volatile("v_accvgpr_write_b32 %0, %1" : "=a"(dst) : "v"(src))
#define DOT4A(acc, wa4, h4) { uint4 t_; \
  asm("v_accvgpr_read_b32 %0, %1" : "=v"(t_.x) : "a"((wa4).x)); \
  asm("v_accvgpr_read_b32 %0, %1" : "=v"(t_.y) : "a"((wa4).y)); \
  asm("v_accvgpr_read_b32 %0, %1" : "=v"(t_.z) : "a"((wa4).z)); \
  asm("v_accvgpr_read_b32 %0, %1" : "=v"(t_.w) : "a"((wa4).w)); \
  DOT4V(acc, t_, h4); }

__device__ __forceinline__ float sigm(float x)   { return 1.0f / (1.0f + __expf(-x)); }
__device__ __forceinline__ float tanh_f(float x) { return 1.0f - 2.0f / (__expf(2.0f * x) + 1.0f); }

// U[256][1024] fp32 -> UT[1024][256] f16 (transposed, k-contiguous)
__global__ __launch_bounds__(256) void convert_u(const float* __restrict__ U,
                                                 _Float16* __restrict__ UT) {
  int i = blockIdx.x * 256 + threadIdx.x;   // 262144
  int n = i >> 8, k = i & 255;
  UT[i] = (_Float16)U[(size_t)k * Zdim + n];
}

// W[256][1024] fp32 -> f16-pair layouts for lstm v9 (512 threads, half-K).
// Thread t (half=t>>8, u=t&255), gate g: col = g*256+u, k2 = half*64 + j*4 + e.
// Slot s = j*4+g (j=0..15):
//  j 0..5   -> Wa[s*512+t]            (AGPR, 24 uint4)
//  j 6..8   -> Wv[(s-24)*512+t]       (VGPR opaque, 12)
//  j 9..12  -> Wl[(s-36)*512+t]       (LDS, 16)
//  j 13..15 -> Ws[(s-52)*512+t]       (L2 stream, 12)
__global__ __launch_bounds__(256) void convert_w9(const float* __restrict__ W,
                                                  uint4* __restrict__ Wa,
                                                  uint4* __restrict__ Wv,
                                                  uint4* __restrict__ Wl,
                                                  uint4* __restrict__ Ws) {
  int i = blockIdx.x * 256 + threadIdx.x;   // 32768 uint4
  if (i >= 32768) return;
  int s = i >> 9, t = i & 511;
  int j = s >> 2, g = s & 3;
  uint4* dst; int idx;
  if (j < 6)       { dst = Wa; idx = s * 512 + t; }
  else if (j < 9)  { dst = Wv; idx = (s - 24) * 512 + t; }
  else if (j < 13) { dst = Wl; idx = (s - 36) * 512 + t; }
  else             { dst = Ws; idx = (s - 52) * 512 + t; }
  int col = g * 256 + (t & 255);
  int kbase = (t >> 8) * 64 + j * 4;
  uint32_t d[4];
#pragma unroll
  for (int e = 0; e < 4; e++) {
    int k2 = kbase + e;
    float w0 = W[(size_t)(2 * k2) * Zdim + col];
    float w1 = W[(size_t)(2 * k2 + 1) * Zdim + col];
    __half2 p = __floats2half2_rn(w0, w1);
    d[e] = __builtin_bit_cast(uint32_t, p);
  }
  dst[idx] = make_uint4(d[0], d[1], d[2], d[3]);
}

// xz[(tloc*64+b)*1024+n] = x[b][t][:] @ U[:,n] + bias[n] via f16 MFMA.
__global__ __launch_bounds__(256) void proj_mfma(
    const float* __restrict__ x, const _Float16* __restrict__ UT,
    const float* __restrict__ bias, float* __restrict__ xz, int t0) {
  __shared__ _Float16 Ax[64][40];
  __shared__ _Float16 Ux[256][40];
  const int tid  = threadIdx.x;
  const int w    = tid >> 6, lane = tid & 63;
  const int lr   = lane & 15, kg = lane >> 4;
  const int n0   = blockIdx.x * 256;
  const int tloc = blockIdx.y;
  const int t    = t0 + tloc;
  const int arow = tid >> 2, ak = (tid & 3) * 8;

  f32x4 acc[4][4];
#pragma unroll
  for (int mi = 0; mi < 4; mi++)
#pragma unroll
    for (int ni = 0; ni < 4; ni++) acc[mi][ni] = f32x4{0.f, 0.f, 0.f, 0.f};

  for (int k0 = 0; k0 < Dsz; k0 += 32) {
    const float* xp = x + ((size_t)arow * Tsz + t) * Dsz + k0 + ak;
    float4 p0 = *(const float4*)xp;
    float4 p1 = *(const float4*)(xp + 4);
    const _Float16* up = UT + (size_t)(n0 + tid) * Dsz + k0;
    f16x8 u0 = *(const f16x8*)up;
    f16x8 u1 = *(const f16x8*)(up + 8);
    f16x8 u2 = *(const f16x8*)(up + 16);
    f16x8 u3 = *(const f16x8*)(up + 24);
    __syncthreads();
    f16x8 a8;
    a8[0] = (_Float16)p0.x; a8[1] = (_Float16)p0.y;
    a8[2] = (_Float16)p0.z; a8[3] = (_Float16)p0.w;
    a8[4] = (_Float16)p1.x; a8[5] = (_Float16)p1.y;
    a8[6] = (_Float16)p1.z; a8[7] = (_Float16)p1.w;
    *(f16x8*)&Ax[arow][ak] = a8;
    *(f16x8*)&Ux[tid][0]  = u0;
    *(f16x8*)&Ux[tid][8]  = u1;
    *(f16x8*)&Ux[tid][16] = u2;
    *(f16x8*)&Ux[tid][24] = u3;
    __syncthreads();
    f16x8 af[4], uf[4];
#pragma unroll
    for (int mi = 0; mi < 4; mi++) af[mi] = *(const f16x8*)&Ax[mi * 16 + lr][kg * 8];
#pragma unroll
    for (int ni = 0; ni < 4; ni++) uf[ni] = *(const f16x8*)&Ux[w * 64 + ni * 16 + lr][kg * 8];
#pragma unroll
    for (int mi = 0; mi < 4; mi++)
#pragma unroll
      for (int ni = 0; ni < 4; ni++)
        acc[mi][ni] = __builtin_amdgcn_mfma_f32_16x16x32_f16(af[mi], uf[ni],
                                                             acc[mi][ni], 0, 0, 0);
  }
#pragma unroll
  for (int ni = 0; ni < 4; ni++) {
    int col = n0 + w * 64 + ni * 16 + lr;
    float bs = bias[col];
#pragma unroll
    for (int mi = 0; mi < 4; mi++) {
      f32x4 v = acc[mi][ni];
#pragma unroll
      for (int r = 0; r < 4; r++) {
        int brow = mi * 16 + kg * 4 + r;
        xz[((size_t)tloc * 64 + brow) * Zdim + col] = v[r] + bs;
      }
    }
  }
}

// One WG (512 thr = 8 waves, 2/SIMD) per batch; static LDS 133 KB -> 1 WG/CU.
// W per thread = 64 uint4: 24 AGPR (accvgpr_read per use) + 12 VGPR opaque +
// 16 LDS (128 KB) + 12 L2-stream (96 KB/step, 3 staggered batches).
__global__ __launch_bounds__(512) void lstm_chunk(
    const float* __restrict__ xz, const uint4* __restrict__ WaB,
    const uint4* __restrict__ WvB, const uint4* __restrict__ WlB,
    const uint4* __restrict__ Ws, float* __restrict__ out,
    uint4* __restrict__ h_state, float* __restrict__ c_state,
    int t0, int Tc, int n_out) {
  __shared__ uint4 Wlds[16 * 512];   // 128 KB resident W (j=9..12)
  __shared__ uint4 hq[2][32];        // 1 KB packed-f16 h, double-buffered
  __shared__ float4 pp[256];         // 4 KB half=1 partials

  const int tid  = threadIdx.x;
  const int b    = blockIdx.x;
  const int half = tid >> 8, u = tid & 255;

  // AGPR-resident W (96 AGPRs on top of the arch-VGPR budget)
  uint4 wa[24];
#pragma unroll
  for (int s = 0; s < 24; s++) {
    uint4 v = WaB[(size_t)s * 512 + tid];
    WR_A(wa[s].x, v.x); WR_A(wa[s].y, v.y);
    WR_A(wa[s].z, v.z); WR_A(wa[s].w, v.w);
  }
  // VGPR-resident W (48 regs), opaque against remat
  uint4 wv[12];
#pragma unroll
  for (int s = 0; s < 12; s++) wv[s] = WvB[(size_t)s * 512 + tid];
#pragma unroll
  for (int s = 0; s < 12; s++)
    asm volatile("" : "+v"(wv[s].x), "+v"(wv[s].y), "+v"(wv[s].z), "+v"(wv[s].w));
  // LDS-resident W
#pragma unroll
  for (int s = 0; s < 16; s++)
    Wlds[s * 512 + tid] = WlB[(size_t)s * 512 + tid];

  float c = 0.0f;
  if (t0 == 0) {
    if (tid < 64) ((uint4*)hq)[tid] = make_uint4(0, 0, 0, 0);
  } else {
    if (tid < 32) ((uint4*)hq)[tid] = h_state[(size_t)b * 32 + tid];
    if (half == 0) c = c_state[(size_t)b * 256 + u];
  }
  __syncthreads();

  const float* xzb = xz + (size_t)b * Zdim + u;
  float nx0 = 0, nx1 = 0, nx2 = 0, nx3 = 0;
  if (half == 0) { nx0 = xzb[0]; nx1 = xzb[256]; nx2 = xzb[512]; nx3 = xzb[768]; }
  const uint4* wsp = Ws + tid;

  for (int tl = 0; tl < Tc; tl++) {
    const int buf = tl & 1;
    const uint4* hb = hq[buf] + half * 16;
    float a0 = 0, a1 = 0, a2 = 0, a3 = 0;

    // issue stream batch A (j=13)
    uint4 sA0 = wsp[0 * 512], sA1 = wsp[1 * 512], sA2 = wsp[2 * 512], sA3 = wsp[3 * 512];
    // AGPR phase j=0..2
#pragma unroll
    for (int j = 0; j < 3; j++) {
      uint4 h4 = hb[j];
      DOT4A(a0, wa[j * 4 + 0], h4); DOT4A(a1, wa[j * 4 + 1], h4);
      DOT4A(a2, wa[j * 4 + 2], h4); DOT4A(a3, wa[j * 4 + 3], h4);
    }
    // issue stream batch B (j=14)
    uint4 sB0 = wsp[4 * 512], sB1 = wsp[5 * 512], sB2 = wsp[6 * 512], sB3 = wsp[7 * 512];
    // AGPR phase j=3..5
#pragma unroll
    for (int j = 3; j < 6; j++) {
      uint4 h4 = hb[j];
      DOT4A(a0, wa[j * 4 + 0], h4); DOT4A(a1, wa[j * 4 + 1], h4);
      DOT4A(a2, wa[j * 4 + 2], h4); DOT4A(a3, wa[j * 4 + 3], h4);
    }
    // consume A (j=13); issue batch C (j=15)
    { uint4 h4 = hb[13];
      DOT4V(a0, sA0, h4); DOT4V(a1, sA1, h4);
      DOT4V(a2, sA2, h4); DOT4V(a3, sA3, h4); }
    uint4 sC0 = wsp[8 * 512], sC1 = wsp[9 * 512], sC2 = wsp[10 * 512], sC3 = wsp[11 * 512];
    // VGPR phase j=6..8
#pragma unroll
    for (int j = 0; j < 3; j++) {
      uint4 h4 = hb[6 + j];
      DOT4V(a0, wv[j * 4 + 0], h4); DOT4V(a1, wv[j * 4 + 1], h4);
      DOT4V(a2, wv[j * 4 + 2], h4); DOT4V(a3, wv[j * 4 + 3], h4);
    }
    // consume B (j=14)
    { uint4 h4 = hb[14];
      DOT4V(a0, sB0, h4); DOT4V(a1, sB1, h4);
      DOT4V(a2, sB2, h4); DOT4V(a3, sB3, h4); }
    // LDS phase j=9..12
#pragma unroll
    for (int jj = 0; jj < 4; jj++) {
      uint4 h4 = hb[9 + jj];
      uint4 w0 = Wlds[(jj * 4 + 0) * 512 + tid];
      uint4 w1 = Wlds[(jj * 4 + 1) * 512 + tid];
      uint4 w2 = Wlds[(jj * 4 + 2) * 512 + tid];
      uint4 w3 = Wlds[(jj * 4 + 3) * 512 + tid];
      DOT4V(a0, w0, h4); DOT4V(a1, w1, h4);
      DOT4V(a2, w2, h4); DOT4V(a3, w3, h4);
    }
    // consume C (j=15)
    { uint4 h4 = hb[15];
      DOT4V(a0, sC0, h4); DOT4V(a1, sC1, h4);
      DOT4V(a2, sC2, h4); DOT4V(a3, sC3, h4); }

    if (half) pp[u] = make_float4(a0, a1, a2, a3);
    __syncthreads();
    if (!half) {
      float4 q = pp[u];
      float z0 = a0 + q.x + nx0, z1 = a1 + q.y + nx1;
      float z2 = a2 + q.z + nx2, z3 = a3 + q.w + nx3;
      if (tl + 1 < Tc) {
        const float* xn = xzb + (size_t)(tl + 1) * (Bsz * Zdim);
        nx0 = xn[0]; nx1 = xn[256]; nx2 = xn[512]; nx3 = xn[768];
      }
      float ig = sigm(z0), fg = sigm(z1), gg = tanh_f(z2), og = sigm(z3);
      c = fg * c + ig * gg;
      float hn = og * tanh_f(c);
      int ot = (t0 + tl) - (Tsz - n_out);
      if (ot >= 0) out[((size_t)b * n_out + ot) * UNITSn + u] = hn;
      ((__half*)hq[buf ^ 1])[u] = __float2half(hn);
    }
    __syncthreads();
  }
  if (tid < 32) h_state[(size_t)b * 32 + tid] = ((uint4*)hq)[(Tc & 1) * 32 + tid];
  if (half == 0) c_state[(size_t)b * 256 + u] = c;
}

extern "C" void kernel_launch(void* const* d_in, const int* in_sizes, int n_in,
                              void* d_out, int out_size, void* d_ws, size_t ws_size,
                              hipStream_t stream) {
  const float* x    = (const float*)d_in[0];
  const float* U    = (const float*)d_in[1];
  const float* W    = (const float*)d_in[2];
  const float* bias = (const float*)d_in[3];
  float* out = (float*)d_out;
  const int n_out = out_size / (Bsz * UNITSn);   // 32

  uint8_t* ws = (uint8_t*)d_ws;
  uint4* Wa       = (uint4*)ws;                    // 192 KB (12288 uint4)
  uint4* Wv       = (uint4*)(ws + (192u << 10));   //  96 KB (6144 uint4)
  uint4* Wl       = (uint4*)(ws + (288u << 10));   // 128 KB (8192 uint4)
  uint4* Ws_      = (uint4*)(ws + (416u << 10));   //  96 KB (6144 uint4)
  _Float16* UT    = (_Float16*)(ws + (512u << 10));// 512 KB
  uint4* h_state  = (uint4*)(ws + (1024u << 10));  //  32 KB
  float* c_state  = (float*)(ws + (1056u << 10));  //  64 KB
  float* xz       = (float*)(ws + (2u << 20));     // Tc*64*1024 fp32

  int Tc = Tsz;
  while (Tc > 1 && (size_t)(2u << 20) + (size_t)Tc * (Bsz * Zdim) * 4 > ws_size) Tc >>= 1;

  convert_w9<<<dim3(128), dim3(256), 0, stream>>>(W, Wa, Wv, Wl, Ws_);
  convert_u<<<dim3(1024), dim3(256), 0, stream>>>(U, UT);

  for (int t0 = 0; t0 < Tsz; t0 += Tc) {
    proj_mfma<<<dim3(4, Tc), dim3(256), 0, stream>>>(x, UT, bias, xz, t0);
    lstm_chunk<<<dim3(Bsz), dim3(512), 0, stream>>>(xz, Wa, Wv, Wl, Ws_,
                                                    out, h_state, c_state,
                                                    t0, Tc, n_out);
  }
}